// Round 17
// baseline (166.750 us; speedup 1.0000x reference)
//
#include <hip/hip_runtime.h>
#include <hip/hip_bf16.h>
#include <stdint.h>

#define NEGV -1e30f

typedef __attribute__((ext_vector_type(8))) __bf16 bf16x8;
typedef __attribute__((ext_vector_type(4))) float f32x4;

__device__ __forceinline__ uint16_t f2bfu(float f){
  __hip_bfloat16 h = __float2bfloat16(f);
  return *reinterpret_cast<const uint16_t*>(&h);
}

// tiled fp32->bf16 transpose helper: out[N][K] = bf16(in[K][N]), 64x64 tile b
__device__ __forceinline__ void dev_transpose(
  const float* __restrict__ in, __hip_bfloat16* __restrict__ out,
  int K, int N, int ktiles, int b, int tid, float* t)
{
  int kt = b % ktiles, nt = b / ktiles;
  int k0 = kt*64, n0 = nt*64;
  int c = tid & 63, rg = tid >> 6;
  #pragma unroll
  for (int rr = 0; rr < 16; ++rr){
    int row = rg + rr*4;
    t[row*65 + c] = in[(k0+row)*N + n0 + c];
  }
  __syncthreads();
  #pragma unroll
  for (int rr = 0; rr < 16; ++rr){
    int row = rg + rr*4;
    out[(n0+row)*K + k0 + c] = __float2bfloat16(t[c*65 + row]);
  }
}

// ---------------- front: child K-split partials (512 blocks) + all weight preps (160 blocks)
__global__ __launch_bounds__(256) void k_front(
    const float* __restrict__ pf, const float* __restrict__ gc,
    const float* __restrict__ gn, const float* __restrict__ Wp,
    const float* __restrict__ Wne, const float* __restrict__ Wch,
    const float* __restrict__ Wc2, const float* __restrict__ Wsem,
    float* __restrict__ pchild, __hip_bfloat16* __restrict__ WeT,
    __hip_bfloat16* __restrict__ WchT, __hip_bfloat16* __restrict__ Wc2T,
    __hip_bfloat16* __restrict__ WsemT)
{
  __shared__ float sh[64*65];
  int bid = blockIdx.x, tid = threadIdx.x;
  if (bid < 512){
    int jb = bid & 63, ks = bid >> 6;
    int i0 = ks*36, i1 = (i0+36 < 282) ? i0+36 : 282;
    if (tid < i1-i0){
      int i = i0 + tid;
      sh[tid] = (i < 256) ? pf[i] : ((i < 272) ? gc[i-256] : gn[i-272]);
    }
    __syncthreads();
    int j0 = jb*1024 + tid*4;
    f32x4 acc = {0,0,0,0};
    #pragma unroll 6
    for (int i = i0; i < i1; ++i){
      f32x4 w = *reinterpret_cast<const f32x4*>(Wp + i*65536 + j0);
      float x = sh[i-i0];
      acc[0] = fmaf(x, w[0], acc[0]);
      acc[1] = fmaf(x, w[1], acc[1]);
      acc[2] = fmaf(x, w[2], acc[2]);
      acc[3] = fmaf(x, w[3], acc[3]);
    }
    *reinterpret_cast<f32x4*>(pchild + ks*65536 + j0) = acc;
  } else if (bid < 544){
    int b = bid - 512; int it = b >> 4;
    dev_transpose(Wne + it*197632 + 512*256, WeT + it*65536, 256, 256, 4, b & 15, tid, sh);
  } else if (bid < 592){
    dev_transpose(Wch, WchT, 768, 256, 12, bid - 544, tid, sh);
  } else if (bid < 608){
    dev_transpose(Wc2, Wc2T, 256, 256, 4, bid - 592, tid, sh);
  } else {
    int b = bid - 608;
    int j = b*4 + (tid>>6), c = tid & 63;
    float v = (c < 50) ? Wsem[j*50+c] : 0.f;
    WsemT[c*256 + j] = __float2bfloat16(v);
  }
}

// ---------------- merged: child reduce + exists (jobs 0..255)  |  ab (jobs 256..511)
__global__ __launch_bounds__(256) void k_reduce_ab(
  const float* __restrict__ pchild, const float* __restrict__ bp,
  const float* __restrict__ Wex, const float* __restrict__ bex,
  const float* __restrict__ Wel,
  float* __restrict__ cf, __hip_bfloat16* __restrict__ cfcb,
  float* __restrict__ exout, int* __restrict__ ok, int* __restrict__ flag,
  float* __restrict__ a, float* __restrict__ b2, float* __restrict__ b2T)
{
  __shared__ float shmem[2][256];
  int bid = blockIdx.x, tid = threadIdx.x;
  if (bid < 256){
    int m = bid;
    int j = m*256 + tid;
    float s = bp[j];
    #pragma unroll
    for (int ks = 0; ks < 8; ++ks) s += pchild[ks*65536 + j];
    s = fmaxf(s, 0.f);
    cf[j] = s;
    cfcb[m*768 + tid] = __float2bfloat16(s);
    shmem[0][tid] = s * Wex[tid];
    __syncthreads();
    float* red = shmem[0];
    for (int st = 128; st > 0; st >>= 1){ if (tid < st) red[tid] += red[tid+st]; __syncthreads(); }
    if (tid == 0){
      float logit = red[0] + bex[0];
      exout[m] = logit;
      ok[m] = logit > 0.f ? 1 : 0;
      if (m == 0) *flag = 0;
    }
  } else {
    int b = bid - 256;
    int sel = b >> 7; int m0 = (b & 127)*2;
    #pragma unroll
    for (int r = 0; r < 2; ++r){
      int j = (m0+r)*256 + tid;
      float s = bp[j];
      #pragma unroll
      for (int ks = 0; ks < 8; ++ks) s += pchild[ks*65536 + j];
      shmem[r][tid] = fmaxf(s, 0.f);
    }
    __syncthreads();
    const float* W = Wel + sel*65536;
    float acc0 = 0.f, acc1 = 0.f;
    #pragma unroll 8
    for (int j = 0; j < 256; ++j){
      float w = W[j*256+tid];
      acc0 = fmaf(shmem[0][j], w, acc0);
      acc1 = fmaf(shmem[1][j], w, acc1);
    }
    float* dst = sel ? b2 : a;
    dst[m0*256+tid] = acc0;
    dst[(m0+1)*256+tid] = acc1;
    if (sel){
      b2T[tid*256 + m0]   = acc0;
      b2T[tid*256 + m0+1] = acc1;
    }
  }
}

// ---------------- ee part (round-8 proven): h-split 2. grid = m(256) x hs(2)
__global__ __launch_bounds__(256) void k_ee_part(
  const float* __restrict__ a, const float* __restrict__ b2T,
  const float* __restrict__ bel, const float* __restrict__ Wee,
  float* __restrict__ pee)
{
  __shared__ float wee[4][128];
  __shared__ float ac[128];
  int bid = blockIdx.x; int m = bid & 255; int hs = bid >> 8;
  int tid = threadIdx.x;
  int h0 = hs*128;
  if (tid < 128){
    ac[tid] = a[m*256 + h0 + tid] + bel[h0 + tid];
    wee[0][tid] = Wee[      h0 + tid];
    wee[1][tid] = Wee[256 + h0 + tid];
  } else {
    int t = tid - 128;
    wee[2][t] = Wee[512 + h0 + t];
    wee[3][t] = Wee[768 + h0 + t];
  }
  __syncthreads();
  int n = tid;
  float e0 = 0.f, e1 = 0.f, e2 = 0.f, e3 = 0.f;
  #pragma unroll 8
  for (int h = 0; h < 128; ++h){
    float el = fmaxf(ac[h] + b2T[(h0+h)*256 + n], 0.f);
    e0 = fmaf(el, wee[0][h], e0);
    e1 = fmaf(el, wee[1][h], e1);
    e2 = fmaf(el, wee[2][h], e2);
    e3 = fmaf(el, wee[3][h], e3);
  }
  f32x4 p; p[0]=e0; p[1]=e1; p[2]=e2; p[3]=e3;
  *reinterpret_cast<f32x4*>(pee + ((hs*256+m)*256 + n)*4) = p;
}

// ---------------- merged: ee combine (jobs 0..255)  |  sd it=0 (jobs 256..511)
__global__ __launch_bounds__(256) void k_eecomb_sd0(
  const float* __restrict__ pee, const float* __restrict__ bee,
  const int* __restrict__ ok, float* __restrict__ eemask,
  float* __restrict__ eeout, int* __restrict__ flag,
  const float* __restrict__ cf, const float* __restrict__ Wne,
  const float* __restrict__ bne, float* __restrict__ sp, float* __restrict__ d)
{
  __shared__ float cfs[2][256];
  int bid = blockIdx.x, tid = threadIdx.x;
  if (bid < 256){
    int m = bid, n = tid;
    f32x4 p0 = *reinterpret_cast<const f32x4*>(pee + ((0*256+m)*256 + n)*4);
    f32x4 p1 = *reinterpret_cast<const f32x4*>(pee + ((1*256+m)*256 + n)*4);
    float e0 = bee[0] + p0[0] + p1[0];
    float e1 = bee[1] + p0[1] + p1[1];
    float e2 = bee[2] + p0[2] + p1[2];
    float e3 = bee[3] + p0[3] + p1[3];
    int idx = (m*256+n)*4;
    f32x4 eo; eo[0]=e0; eo[1]=e1; eo[2]=e2; eo[3]=e3;
    *reinterpret_cast<f32x4*>(eeout + idx) = eo;
    int okmn = ok[m] & ok[n];
    f32x4 em;
    em[0] = (okmn && e0 > 0.f) ? e0 : NEGV;
    em[1] = (okmn && e1 > 0.f) ? e1 : NEGV;
    em[2] = (okmn && e2 > 0.f) ? e2 : NEGV;
    em[3] = (okmn && e3 > 0.f) ? e3 : NEGV;
    *reinterpret_cast<f32x4*>(eemask + idx) = em;
    if (em[0] > -1e29f || em[1] > -1e29f || em[2] > -1e29f || em[3] > -1e29f) atomicOr(flag, 1);
  } else {
    int b = bid - 256;
    int sel = b >> 7; int m0 = (b & 127)*2;
    cfs[0][tid] = cf[m0*256 + tid];
    cfs[1][tid] = cf[(m0+1)*256 + tid];
    __syncthreads();
    const float* W = Wne + sel*65536;
    float bias = sel ? 0.f : bne[tid];
    float acc0 = bias, acc1 = bias;
    #pragma unroll 8
    for (int j = 0; j < 256; ++j){
      float w = W[j*256+tid];
      acc0 = fmaf(cfs[0][j], w, acc0);
      acc1 = fmaf(cfs[1][j], w, acc1);
    }
    float* dst = sel ? d : sp;
    dst[m0*256+tid] = acc0;
    dst[(m0+1)*256+tid] = acc1;
  }
}

// ---------------- s'[m,k]=cf@Ws + b_ne ; d[n,k]=cf@Wd  (RB=2, grid 256) — it=1 only
__global__ __launch_bounds__(256) void k_sd(
  const float* __restrict__ cf, const float* __restrict__ Wne,
  const float* __restrict__ bne, float* __restrict__ sp, float* __restrict__ d, int it)
{
  __shared__ float cfs[2][256];
  int bid = blockIdx.x; int sel = bid >> 7; int m0 = (bid & 127)*2; int tid = threadIdx.x;
  cfs[0][tid] = cf[m0*256 + tid];
  cfs[1][tid] = cf[(m0+1)*256 + tid];
  __syncthreads();
  const float* W = Wne + it*197632 + sel*65536;
  float bias = sel ? 0.f : bne[it*256+tid];
  float acc0 = bias, acc1 = bias;
  #pragma unroll 8
  for (int j = 0; j < 256; ++j){
    float w = W[j*256+tid];
    acc0 = fmaf(cfs[0][j], w, acc0);
    acc1 = fmaf(cfs[1][j], w, acc1);
  }
  float* dst = sel ? d : sp;
  dst[m0*256+tid] = acc0;
  dst[(m0+1)*256+tid] = acc1;
}

// ---------------- fused v4b: v4 (64-row chunks) + me/dv prefetched one chunk ahead
// Same values, same order, same barrier count as v4 -> bit-identical output.
__global__ __launch_bounds__(256,2) void k_fused_v4b(
  const float* __restrict__ a, const float* __restrict__ bel,
  const float* __restrict__ b2, const __hip_bfloat16* __restrict__ wet,
  const float* __restrict__ sp, const float* __restrict__ dmat,
  const float* __restrict__ eemask, const float* __restrict__ Wne_it,
  float* __restrict__ cf, __hip_bfloat16* __restrict__ cfcb,
  const int* __restrict__ flag, int it)
{
  __shared__ __attribute__((aligned(16))) char weS[32768];
  __shared__ __attribute__((aligned(16))) char elS[32768];
  __shared__ float acs[256];
  __shared__ float red[4][64];
  int bid = blockIdx.x; int m = bid >> 2, kc = bid & 3;
  int tid = threadIdx.x;
  acs[tid] = a[m*256+tid] + bel[tid];
  const char* wsrc = reinterpret_cast<const char*>(wet + kc*16384);
  #pragma unroll
  for (int p = 0; p < 8; ++p){
    int i = p*256 + tid;
    int row = i >> 5, colb = (i & 31) << 4;
    int byte = (row << 9) | colb;
    *reinterpret_cast<bf16x8*>(weS + (byte ^ ((row & 7) << 4))) =
      *reinterpret_cast<const bf16x8*>(wsrc + byte);
  }
  __syncthreads();

  int w = tid >> 6, l = tid & 63, l15 = l & 15, lg = l >> 4;
  float spv[4], wtv[4][4];
  #pragma unroll
  for (int kt = 0; kt < 4; ++kt){
    int kcol = kc*64 + kt*16 + l15;
    spv[kt] = sp[m*256+kcol];
    #pragma unroll
    for (int t = 0; t < 4; ++t) wtv[t][kt] = Wne_it[(768+t)*256 + kcol];
  }
  int rowb[4], rowx[4];
  #pragma unroll
  for (int kt = 0; kt < 4; ++kt){
    int row = kt*16 + l15;
    rowb[kt] = row << 9;
    rowx[kt] = (row & 7) << 4;
  }
  int arow = w*16 + l15;
  float runmax[4] = {NEGV, NEGV, NEGV, NEGV};

  // prologue: prefetch chunk 0's b2 values + me/dv epilogue operands
  f32x4 bv[16];
  #pragma unroll
  for (int p = 0; p < 16; ++p){
    int idx = p*256 + tid;
    int row = idx >> 6, h4 = (idx & 63) << 2;
    bv[p] = *reinterpret_cast<const f32x4*>(b2 + (size_t)(row)*256 + h4);
  }
  f32x4 me[4];
  float dv[4][4];
  {
    int nb0 = w*16;
    #pragma unroll
    for (int r = 0; r < 4; ++r){
      int n = nb0 + lg*4 + r;
      me[r] = *reinterpret_cast<const f32x4*>(eemask + (m*256+n)*4);
      const float* dr = dmat + n*256 + kc*64;
      #pragma unroll
      for (int kt = 0; kt < 4; ++kt) dv[r][kt] = dr[kt*16 + l15];
    }
  }

  for (int c = 0; c < 4; ++c){
    // ---- stage elS from prefetched regs (cvt + swizzled write)
    #pragma unroll
    for (int p = 0; p < 16; ++p){
      int idx = p*256 + tid;
      int row = idx >> 6;
      int h4 = (idx & 63) << 2;
      f32x4 av = *reinterpret_cast<const f32x4*>(acs + h4);
      union { uint16_t u[4]; uint64_t d; } pk;
      #pragma unroll
      for (int j = 0; j < 4; ++j) pk.u[j] = f2bfu(fmaxf(av[j]+bv[p][j], 0.f));
      int byte = (row << 9) | (h4 << 1);
      *reinterpret_cast<uint64_t*>(elS + (byte ^ ((row & 7) << 4))) = pk.d;
    }
    __syncthreads();

    // current chunk's epilogue operands (already in regs)
    f32x4 meC[4];
    float dvC[4][4];
    #pragma unroll
    for (int r = 0; r < 4; ++r){
      meC[r] = me[r];
      #pragma unroll
      for (int kt = 0; kt < 4; ++kt) dvC[r][kt] = dv[r][kt];
    }

    // ---- prefetch next chunk's b2 + me/dv (latency hides under MFMA below)
    if (c < 3){
      #pragma unroll
      for (int p = 0; p < 16; ++p){
        int idx = p*256 + tid;
        int row = idx >> 6, h4 = (idx & 63) << 2;
        bv[p] = *reinterpret_cast<const f32x4*>(b2 + (size_t)((c+1)*64+row)*256 + h4);
      }
      int nbN = (c+1)*64 + w*16;
      #pragma unroll
      for (int r = 0; r < 4; ++r){
        int n = nbN + lg*4 + r;
        me[r] = *reinterpret_cast<const f32x4*>(eemask + (m*256+n)*4);
        const float* dr = dmat + n*256 + kc*64;
        #pragma unroll
        for (int kt = 0; kt < 4; ++kt) dv[r][kt] = dr[kt*16 + l15];
      }
    }

    // ---- compute: wave w owns rows nb..nb+16
    bf16x8 Af[8];
    #pragma unroll
    for (int kk = 0; kk < 8; ++kk)
      Af[kk] = *reinterpret_cast<const bf16x8*>(elS + (((arow << 9) | (kk*64 + lg*16)) ^ ((arow & 7) << 4)));

    f32x4 acc0 = {0,0,0,0}, acc1 = {0,0,0,0}, acc2 = {0,0,0,0}, acc3 = {0,0,0,0};
    #pragma unroll
    for (int kk = 0; kk < 8; ++kk){
      int cc = kk*64 + lg*16;
      bf16x8 B0 = *reinterpret_cast<const bf16x8*>(weS + ((rowb[0] + cc) ^ rowx[0]));
      bf16x8 B1 = *reinterpret_cast<const bf16x8*>(weS + ((rowb[1] + cc) ^ rowx[1]));
      bf16x8 B2 = *reinterpret_cast<const bf16x8*>(weS + ((rowb[2] + cc) ^ rowx[2]));
      bf16x8 B3 = *reinterpret_cast<const bf16x8*>(weS + ((rowb[3] + cc) ^ rowx[3]));
      acc0 = __builtin_amdgcn_mfma_f32_16x16x32_bf16(Af[kk], B0, acc0, 0, 0, 0);
      acc1 = __builtin_amdgcn_mfma_f32_16x16x32_bf16(Af[kk], B1, acc1, 0, 0, 0);
      acc2 = __builtin_amdgcn_mfma_f32_16x16x32_bf16(Af[kk], B2, acc2, 0, 0, 0);
      acc3 = __builtin_amdgcn_mfma_f32_16x16x32_bf16(Af[kk], B3, acc3, 0, 0, 0);
    }
    #pragma unroll
    for (int r = 0; r < 4; ++r){
      float Ed0 = acc0[r] + dvC[r][0] + spv[0];
      float Ed1 = acc1[r] + dvC[r][1] + spv[1];
      float Ed2 = acc2[r] + dvC[r][2] + spv[2];
      float Ed3 = acc3[r] + dvC[r][3] + spv[3];
      #pragma unroll
      for (int t = 0; t < 4; ++t){
        if (meC[r][t] > -1e29f){
          runmax[0] = fmaxf(runmax[0], fmaf(meC[r][t], wtv[t][0], Ed0));
          runmax[1] = fmaxf(runmax[1], fmaf(meC[r][t], wtv[t][1], Ed1));
          runmax[2] = fmaxf(runmax[2], fmaf(meC[r][t], wtv[t][2], Ed2));
          runmax[3] = fmaxf(runmax[3], fmaf(meC[r][t], wtv[t][3], Ed3));
        }
      }
    }
    __syncthreads();   // elS consumed; safe to overwrite next chunk
  }
  #pragma unroll
  for (int kt = 0; kt < 4; ++kt){
    float v = runmax[kt];
    v = fmaxf(v, __shfl_xor(v, 16));
    v = fmaxf(v, __shfl_xor(v, 32));
    if (l < 16) red[w][kt*16 + l] = v;
  }
  __syncthreads();
  if (tid < 64){
    float v = fmaxf(fmaxf(red[0][tid], red[1][tid]), fmaxf(red[2][tid], red[3][tid]));
    float nv = fmaxf(v, 0.f);
    int kcol = kc*64 + tid;
    float outv = (*flag) ? nv : cf[m*256+kcol];
    cf[m*256+kcol] = outv;
    cfcb[m*768 + 256*(it+1) + kcol] = __float2bfloat16(outv);
  }
}

// ---------------- final MFMA: ch = relu(cfc@Wch+b); feats = relu(ch@Wc2+b); sem = ch@Wsem+b
__global__ __launch_bounds__(256) void k_final_mfma(
  const __hip_bfloat16* __restrict__ cfcb, const __hip_bfloat16* __restrict__ WchT,
  const float* __restrict__ bch, const __hip_bfloat16* __restrict__ Wc2T,
  const float* __restrict__ bc2, const __hip_bfloat16* __restrict__ WsemT,
  const float* __restrict__ bsem, float* __restrict__ feats_out,
  float* __restrict__ sem_out)
{
  __shared__ char chs[8192];
  int tid = threadIdx.x; int w = tid>>6, l = tid&63, l15 = l&15, lg = l>>4;
  int m0 = blockIdx.x*16;

  f32x4 acc[4] = {{0,0,0,0},{0,0,0,0},{0,0,0,0},{0,0,0,0}};
  const __hip_bfloat16* Aptr = cfcb + (m0 + l15)*768;
  #pragma unroll 2
  for (int ks = 0; ks < 24; ++ks){
    int k0 = ks*32 + lg*8;
    bf16x8 Af = *reinterpret_cast<const bf16x8*>(Aptr + k0);
    #pragma unroll
    for (int nt = 0; nt < 4; ++nt){
      int col = w*64 + nt*16 + l15;
      bf16x8 Bf = *reinterpret_cast<const bf16x8*>(WchT + col*768 + k0);
      acc[nt] = __builtin_amdgcn_mfma_f32_16x16x32_bf16(Af, Bf, acc[nt], 0, 0, 0);
    }
  }
  #pragma unroll
  for (int nt = 0; nt < 4; ++nt){
    int col = w*64 + nt*16 + l15;
    float bias = bch[col];
    #pragma unroll
    for (int r = 0; r < 4; ++r){
      int row = lg*4 + r;
      float v = fmaxf(acc[nt][r] + bias, 0.f);
      int byte = ((row*256 + col)*2) ^ ((row&7)<<4);
      *reinterpret_cast<__hip_bfloat16*>(chs + byte) = __float2bfloat16(v);
    }
  }
  __syncthreads();

  f32x4 accf[4] = {{0,0,0,0},{0,0,0,0},{0,0,0,0},{0,0,0,0}};
  f32x4 accs = {0,0,0,0};
  int cols_sem = w*16 + l15;
  #pragma unroll 2
  for (int ks = 0; ks < 8; ++ks){
    int k0 = ks*32 + lg*8;
    int byteA = (l15*512 + k0*2) ^ ((l15&7)<<4);
    bf16x8 Af = *reinterpret_cast<const bf16x8*>(chs + byteA);
    #pragma unroll
    for (int nt = 0; nt < 4; ++nt){
      int col = w*64 + nt*16 + l15;
      bf16x8 Bf = *reinterpret_cast<const bf16x8*>(Wc2T + col*256 + k0);
      accf[nt] = __builtin_amdgcn_mfma_f32_16x16x32_bf16(Af, Bf, accf[nt], 0, 0, 0);
    }
    bf16x8 Bs = *reinterpret_cast<const bf16x8*>(WsemT + cols_sem*256 + k0);
    accs = __builtin_amdgcn_mfma_f32_16x16x32_bf16(Af, Bs, accs, 0, 0, 0);
  }
  #pragma unroll
  for (int nt = 0; nt < 4; ++nt){
    int col = w*64 + nt*16 + l15;
    float bias = bc2[col];
    #pragma unroll
    for (int r = 0; r < 4; ++r){
      int row = m0 + lg*4 + r;
      feats_out[row*256 + col] = fmaxf(accf[nt][r] + bias, 0.f);
    }
  }
  if (cols_sem < 50){
    float bias = bsem[cols_sem];
    #pragma unroll
    for (int r = 0; r < 4; ++r){
      int row = m0 + lg*4 + r;
      sem_out[row*50 + cols_sem] = accs[r] + bias;
    }
  }
}

extern "C" void kernel_launch(void* const* d_in, const int* in_sizes, int n_in,
                              void* d_out, int out_size, void* d_ws, size_t ws_size,
                              hipStream_t stream)
{
  const float* pf  = (const float*)d_in[0];
  const float* gc  = (const float*)d_in[1];
  const float* gn  = (const float*)d_in[2];
  const float* Wp  = (const float*)d_in[3];
  const float* bp  = (const float*)d_in[4];
  const float* Wex = (const float*)d_in[5];
  const float* bex = (const float*)d_in[6];
  const float* Wsem= (const float*)d_in[7];
  const float* bsem= (const float*)d_in[8];
  const float* Wel = (const float*)d_in[9];
  const float* bel = (const float*)d_in[10];
  const float* Wee = (const float*)d_in[11];
  const float* bee = (const float*)d_in[12];
  const float* Wne = (const float*)d_in[13];
  const float* bne = (const float*)d_in[14];
  const float* Wch = (const float*)d_in[15];
  const float* bch = (const float*)d_in[16];
  const float* Wc2 = (const float*)d_in[17];
  const float* bc2 = (const float*)d_in[18];

  float* out = (float*)d_out;
  float* feats_out = out;             // 65536
  float* sem_out   = out + 65536;     // 12800
  float* ex_out    = out + 78336;     // 256
  float* ee_out    = out + 78592;     // 262144

  char* ws = (char*)d_ws;
  float* cf    = (float*)(ws);                       // 256 KB
  float* a_    = (float*)(ws + ( 256u<<10));         // 256 KB
  float* b2_   = (float*)(ws + ( 512u<<10));         // 256 KB
  float* b2T   = (float*)(ws + ( 768u<<10));         // 256 KB
  float* sp_   = (float*)(ws + (1024u<<10));         // 256 KB
  float* dmat  = (float*)(ws + (1280u<<10));         // 256 KB
  float* eem   = (float*)(ws + (1536u<<10));         // 1 MB
  __hip_bfloat16* WeT   = (__hip_bfloat16*)(ws + (2560u<<10)); // 256 KB
  __hip_bfloat16* cfcb  = (__hip_bfloat16*)(ws + (2816u<<10)); // 384 KB
  __hip_bfloat16* WchT  = (__hip_bfloat16*)(ws + (3200u<<10)); // 384 KB
  __hip_bfloat16* Wc2T  = (__hip_bfloat16*)(ws + (3584u<<10)); // 128 KB
  __hip_bfloat16* WsemT = (__hip_bfloat16*)(ws + (3712u<<10)); //  32 KB
  int* ok   = (int*)(ws + (3744u<<10));
  int* flag = ok + 256;
  float* pchild = (float*)(ws + (3776u<<10));        // 2 MB (time-shared with pee)
  float* pee    = pchild;

  k_front<<<672,256,0,stream>>>(pf,gc,gn,Wp,Wne,Wch,Wc2,Wsem,
                                pchild,WeT,WchT,Wc2T,WsemT);
  k_reduce_ab<<<512,256,0,stream>>>(pchild,bp,Wex,bex,Wel,cf,cfcb,ex_out,ok,flag,a_,b2_,b2T);
  k_ee_part<<<512,256,0,stream>>>(a_,b2T,bel,Wee,pee);
  k_eecomb_sd0<<<512,256,0,stream>>>(pee,bee,ok,eem,ee_out,flag,cf,Wne,bne,sp_,dmat);
  k_fused_v4b<<<1024,256,0,stream>>>(a_,bel,b2_,WeT,sp_,dmat,eem,Wne,cf,cfcb,flag,0);
  k_sd<<<256,256,0,stream>>>(cf,Wne,bne,sp_,dmat,1);
  k_fused_v4b<<<1024,256,0,stream>>>(a_,bel,b2_,WeT + 65536,sp_,dmat,eem,
                                     Wne + 197632,cf,cfcb,flag,1);
  k_final_mfma<<<16,256,0,stream>>>(cfcb,WchT,bch,Wc2T,bc2,WsemT,bsem,feats_out,sem_out);
}

// Round 18
// 145.003 us; speedup vs baseline: 1.1500x; 1.1500x over previous
//
#include <hip/hip_runtime.h>
#include <hip/hip_bf16.h>
#include <stdint.h>

#define NEGV -1e30f

typedef __attribute__((ext_vector_type(8))) __bf16 bf16x8;
typedef __attribute__((ext_vector_type(4))) float f32x4;

__device__ __forceinline__ uint16_t f2bfu(float f){
  __hip_bfloat16 h = __float2bfloat16(f);
  return *reinterpret_cast<const uint16_t*>(&h);
}

// tiled fp32->bf16 transpose helper: out[N][K] = bf16(in[K][N]), 64x64 tile b
__device__ __forceinline__ void dev_transpose(
  const float* __restrict__ in, __hip_bfloat16* __restrict__ out,
  int K, int N, int ktiles, int b, int tid, float* t)
{
  int kt = b % ktiles, nt = b / ktiles;
  int k0 = kt*64, n0 = nt*64;
  int c = tid & 63, rg = tid >> 6;
  #pragma unroll
  for (int rr = 0; rr < 16; ++rr){
    int row = rg + rr*4;
    t[row*65 + c] = in[(k0+row)*N + n0 + c];
  }
  __syncthreads();
  #pragma unroll
  for (int rr = 0; rr < 16; ++rr){
    int row = rg + rr*4;
    out[(n0+row)*K + k0 + c] = __float2bfloat16(t[c*65 + row]);
  }
}

// ---------------- front: child K-split partials (512 blocks) + all weight preps (160 blocks)
__global__ __launch_bounds__(256) void k_front(
    const float* __restrict__ pf, const float* __restrict__ gc,
    const float* __restrict__ gn, const float* __restrict__ Wp,
    const float* __restrict__ Wne, const float* __restrict__ Wch,
    const float* __restrict__ Wc2, const float* __restrict__ Wsem,
    float* __restrict__ pchild, __hip_bfloat16* __restrict__ WeT,
    __hip_bfloat16* __restrict__ WchT, __hip_bfloat16* __restrict__ Wc2T,
    __hip_bfloat16* __restrict__ WsemT)
{
  __shared__ float sh[64*65];
  int bid = blockIdx.x, tid = threadIdx.x;
  if (bid < 512){
    int jb = bid & 63, ks = bid >> 6;
    int i0 = ks*36, i1 = (i0+36 < 282) ? i0+36 : 282;
    if (tid < i1-i0){
      int i = i0 + tid;
      sh[tid] = (i < 256) ? pf[i] : ((i < 272) ? gc[i-256] : gn[i-272]);
    }
    __syncthreads();
    int j0 = jb*1024 + tid*4;
    f32x4 acc = {0,0,0,0};
    #pragma unroll 6
    for (int i = i0; i < i1; ++i){
      f32x4 w = *reinterpret_cast<const f32x4*>(Wp + i*65536 + j0);
      float x = sh[i-i0];
      acc[0] = fmaf(x, w[0], acc[0]);
      acc[1] = fmaf(x, w[1], acc[1]);
      acc[2] = fmaf(x, w[2], acc[2]);
      acc[3] = fmaf(x, w[3], acc[3]);
    }
    *reinterpret_cast<f32x4*>(pchild + ks*65536 + j0) = acc;
  } else if (bid < 544){
    int b = bid - 512; int it = b >> 4;
    dev_transpose(Wne + it*197632 + 512*256, WeT + it*65536, 256, 256, 4, b & 15, tid, sh);
  } else if (bid < 592){
    dev_transpose(Wch, WchT, 768, 256, 12, bid - 544, tid, sh);
  } else if (bid < 608){
    dev_transpose(Wc2, Wc2T, 256, 256, 4, bid - 592, tid, sh);
  } else {
    int b = bid - 608;
    int j = b*4 + (tid>>6), c = tid & 63;
    float v = (c < 50) ? Wsem[j*50+c] : 0.f;
    WsemT[c*256 + j] = __float2bfloat16(v);
  }
}

// ---------------- merged: child reduce + exists (jobs 0..255)  |  ab (jobs 256..511)
// ab jobs recompute their 2 cf rows from pchild with the SAME summation order ->
// bit-identical cf values, no cross-job dependency. sel=1 jobs also write b2T.
__global__ __launch_bounds__(256) void k_reduce_ab(
  const float* __restrict__ pchild, const float* __restrict__ bp,
  const float* __restrict__ Wex, const float* __restrict__ bex,
  const float* __restrict__ Wel,
  float* __restrict__ cf, __hip_bfloat16* __restrict__ cfcb,
  float* __restrict__ exout, int* __restrict__ ok, int* __restrict__ flag,
  float* __restrict__ a, float* __restrict__ b2, float* __restrict__ b2T)
{
  __shared__ float shmem[2][256];
  int bid = blockIdx.x, tid = threadIdx.x;
  if (bid < 256){
    int m = bid;
    int j = m*256 + tid;
    float s = bp[j];
    #pragma unroll
    for (int ks = 0; ks < 8; ++ks) s += pchild[ks*65536 + j];
    s = fmaxf(s, 0.f);
    cf[j] = s;
    cfcb[m*768 + tid] = __float2bfloat16(s);
    shmem[0][tid] = s * Wex[tid];
    __syncthreads();
    float* red = shmem[0];
    for (int st = 128; st > 0; st >>= 1){ if (tid < st) red[tid] += red[tid+st]; __syncthreads(); }
    if (tid == 0){
      float logit = red[0] + bex[0];
      exout[m] = logit;
      ok[m] = logit > 0.f ? 1 : 0;
      if (m == 0) *flag = 0;
    }
  } else {
    int b = bid - 256;
    int sel = b >> 7; int m0 = (b & 127)*2;
    #pragma unroll
    for (int r = 0; r < 2; ++r){
      int j = (m0+r)*256 + tid;
      float s = bp[j];
      #pragma unroll
      for (int ks = 0; ks < 8; ++ks) s += pchild[ks*65536 + j];
      shmem[r][tid] = fmaxf(s, 0.f);
    }
    __syncthreads();
    const float* W = Wel + sel*65536;
    float acc0 = 0.f, acc1 = 0.f;
    #pragma unroll 8
    for (int j = 0; j < 256; ++j){
      float w = W[j*256+tid];
      acc0 = fmaf(shmem[0][j], w, acc0);
      acc1 = fmaf(shmem[1][j], w, acc1);
    }
    float* dst = sel ? b2 : a;
    dst[m0*256+tid] = acc0;
    dst[(m0+1)*256+tid] = acc1;
    if (sel){
      b2T[tid*256 + m0]   = acc0;
      b2T[tid*256 + m0+1] = acc1;
    }
  }
}

// ---------------- ee part (round-8 proven): h-split 2. grid = m(256) x hs(2)
__global__ __launch_bounds__(256) void k_ee_part(
  const float* __restrict__ a, const float* __restrict__ b2T,
  const float* __restrict__ bel, const float* __restrict__ Wee,
  float* __restrict__ pee)
{
  __shared__ float wee[4][128];
  __shared__ float ac[128];
  int bid = blockIdx.x; int m = bid & 255; int hs = bid >> 8;
  int tid = threadIdx.x;
  int h0 = hs*128;
  if (tid < 128){
    ac[tid] = a[m*256 + h0 + tid] + bel[h0 + tid];
    wee[0][tid] = Wee[      h0 + tid];
    wee[1][tid] = Wee[256 + h0 + tid];
  } else {
    int t = tid - 128;
    wee[2][t] = Wee[512 + h0 + t];
    wee[3][t] = Wee[768 + h0 + t];
  }
  __syncthreads();
  int n = tid;
  float e0 = 0.f, e1 = 0.f, e2 = 0.f, e3 = 0.f;
  #pragma unroll 8
  for (int h = 0; h < 128; ++h){
    float el = fmaxf(ac[h] + b2T[(h0+h)*256 + n], 0.f);
    e0 = fmaf(el, wee[0][h], e0);
    e1 = fmaf(el, wee[1][h], e1);
    e2 = fmaf(el, wee[2][h], e2);
    e3 = fmaf(el, wee[3][h], e3);
  }
  f32x4 p; p[0]=e0; p[1]=e1; p[2]=e2; p[3]=e3;
  *reinterpret_cast<f32x4*>(pee + ((hs*256+m)*256 + n)*4) = p;
}

// ---------------- merged: ee combine (jobs 0..255)  |  sd it=0 (jobs 256..511)
__global__ __launch_bounds__(256) void k_eecomb_sd0(
  const float* __restrict__ pee, const float* __restrict__ bee,
  const int* __restrict__ ok, float* __restrict__ eemask,
  float* __restrict__ eeout, int* __restrict__ flag,
  const float* __restrict__ cf, const float* __restrict__ Wne,
  const float* __restrict__ bne, float* __restrict__ sp, float* __restrict__ d)
{
  __shared__ float cfs[2][256];
  int bid = blockIdx.x, tid = threadIdx.x;
  if (bid < 256){
    int m = bid, n = tid;
    f32x4 p0 = *reinterpret_cast<const f32x4*>(pee + ((0*256+m)*256 + n)*4);
    f32x4 p1 = *reinterpret_cast<const f32x4*>(pee + ((1*256+m)*256 + n)*4);
    float e0 = bee[0] + p0[0] + p1[0];
    float e1 = bee[1] + p0[1] + p1[1];
    float e2 = bee[2] + p0[2] + p1[2];
    float e3 = bee[3] + p0[3] + p1[3];
    int idx = (m*256+n)*4;
    f32x4 eo; eo[0]=e0; eo[1]=e1; eo[2]=e2; eo[3]=e3;
    *reinterpret_cast<f32x4*>(eeout + idx) = eo;
    int okmn = ok[m] & ok[n];
    f32x4 em;
    em[0] = (okmn && e0 > 0.f) ? e0 : NEGV;
    em[1] = (okmn && e1 > 0.f) ? e1 : NEGV;
    em[2] = (okmn && e2 > 0.f) ? e2 : NEGV;
    em[3] = (okmn && e3 > 0.f) ? e3 : NEGV;
    *reinterpret_cast<f32x4*>(eemask + idx) = em;
    if (em[0] > -1e29f || em[1] > -1e29f || em[2] > -1e29f || em[3] > -1e29f) atomicOr(flag, 1);
  } else {
    int b = bid - 256;
    int sel = b >> 7; int m0 = (b & 127)*2;
    cfs[0][tid] = cf[m0*256 + tid];
    cfs[1][tid] = cf[(m0+1)*256 + tid];
    __syncthreads();
    const float* W = Wne + sel*65536;
    float bias = sel ? 0.f : bne[tid];
    float acc0 = bias, acc1 = bias;
    #pragma unroll 8
    for (int j = 0; j < 256; ++j){
      float w = W[j*256+tid];
      acc0 = fmaf(cfs[0][j], w, acc0);
      acc1 = fmaf(cfs[1][j], w, acc1);
    }
    float* dst = sel ? d : sp;
    dst[m0*256+tid] = acc0;
    dst[(m0+1)*256+tid] = acc1;
  }
}

// ---------------- s'[m,k]=cf@Ws + b_ne ; d[n,k]=cf@Wd  (RB=2, grid 256) — it=1 only
__global__ __launch_bounds__(256) void k_sd(
  const float* __restrict__ cf, const float* __restrict__ Wne,
  const float* __restrict__ bne, float* __restrict__ sp, float* __restrict__ d, int it)
{
  __shared__ float cfs[2][256];
  int bid = blockIdx.x; int sel = bid >> 7; int m0 = (bid & 127)*2; int tid = threadIdx.x;
  cfs[0][tid] = cf[m0*256 + tid];
  cfs[1][tid] = cf[(m0+1)*256 + tid];
  __syncthreads();
  const float* W = Wne + it*197632 + sel*65536;
  float bias = sel ? 0.f : bne[it*256+tid];
  float acc0 = bias, acc1 = bias;
  #pragma unroll 8
  for (int j = 0; j < 256; ++j){
    float w = W[j*256+tid];
    acc0 = fmaf(cfs[0][j], w, acc0);
    acc1 = fmaf(cfs[1][j], w, acc1);
  }
  float* dst = sel ? d : sp;
  dst[m0*256+tid] = acc0;
  dst[(m0+1)*256+tid] = acc1;
}

// ---------------- fused v4: v3 + T14 async-STAGE split (prefetch next chunk's b2
// into regs right after the stage barrier; cvt+LDS-write next iteration).
// Same values, same order, same barrier count as v3 -> bit-identical output.
__global__ __launch_bounds__(256,2) void k_fused_v4(
  const float* __restrict__ a, const float* __restrict__ bel,
  const float* __restrict__ b2, const __hip_bfloat16* __restrict__ wet,
  const float* __restrict__ sp, const float* __restrict__ dmat,
  const float* __restrict__ eemask, const float* __restrict__ Wne_it,
  float* __restrict__ cf, __hip_bfloat16* __restrict__ cfcb,
  const int* __restrict__ flag, int it)
{
  __shared__ __attribute__((aligned(16))) char weS[32768];
  __shared__ __attribute__((aligned(16))) char elS[32768];
  __shared__ float acs[256];
  __shared__ float red[4][64];
  int bid = blockIdx.x; int m = bid >> 2, kc = bid & 3;
  int tid = threadIdx.x;
  acs[tid] = a[m*256+tid] + bel[tid];
  const char* wsrc = reinterpret_cast<const char*>(wet + kc*16384);
  #pragma unroll
  for (int p = 0; p < 8; ++p){
    int i = p*256 + tid;
    int row = i >> 5, colb = (i & 31) << 4;
    int byte = (row << 9) | colb;
    *reinterpret_cast<bf16x8*>(weS + (byte ^ ((row & 7) << 4))) =
      *reinterpret_cast<const bf16x8*>(wsrc + byte);
  }
  __syncthreads();

  int w = tid >> 6, l = tid & 63, l15 = l & 15, lg = l >> 4;
  float spv[4], wtv[4][4];
  #pragma unroll
  for (int kt = 0; kt < 4; ++kt){
    int kcol = kc*64 + kt*16 + l15;
    spv[kt] = sp[m*256+kcol];
    #pragma unroll
    for (int t = 0; t < 4; ++t) wtv[t][kt] = Wne_it[(768+t)*256 + kcol];
  }
  int rowb[4], rowx[4];
  #pragma unroll
  for (int kt = 0; kt < 4; ++kt){
    int row = kt*16 + l15;
    rowb[kt] = row << 9;
    rowx[kt] = (row & 7) << 4;
  }
  int arow = w*16 + l15;
  float runmax[4] = {NEGV, NEGV, NEGV, NEGV};

  // prologue: prefetch chunk 0's b2 values into regs
  f32x4 bv[16];
  #pragma unroll
  for (int p = 0; p < 16; ++p){
    int idx = p*256 + tid;
    int row = idx >> 6, h4 = (idx & 63) << 2;
    bv[p] = *reinterpret_cast<const f32x4*>(b2 + (size_t)(row)*256 + h4);
  }

  for (int c = 0; c < 4; ++c){
    // ---- stage elS from prefetched regs (cvt + swizzled write)
    #pragma unroll
    for (int p = 0; p < 16; ++p){
      int idx = p*256 + tid;
      int row = idx >> 6;
      int h4 = (idx & 63) << 2;
      f32x4 av = *reinterpret_cast<const f32x4*>(acs + h4);
      union { uint16_t u[4]; uint64_t d; } pk;
      #pragma unroll
      for (int j = 0; j < 4; ++j) pk.u[j] = f2bfu(fmaxf(av[j]+bv[p][j], 0.f));
      int byte = (row << 9) | (h4 << 1);
      *reinterpret_cast<uint64_t*>(elS + (byte ^ ((row & 7) << 4))) = pk.d;
    }
    __syncthreads();

    // ---- prefetch next chunk's b2 (latency hides under MFMA below)
    if (c < 3){
      #pragma unroll
      for (int p = 0; p < 16; ++p){
        int idx = p*256 + tid;
        int row = idx >> 6, h4 = (idx & 63) << 2;
        bv[p] = *reinterpret_cast<const f32x4*>(b2 + (size_t)((c+1)*64+row)*256 + h4);
      }
    }

    // ---- compute: wave w owns rows nb..nb+16
    int nb = c*64 + w*16;
    f32x4 me[4];
    float dv[4][4];
    #pragma unroll
    for (int r = 0; r < 4; ++r){
      int n = nb + lg*4 + r;
      me[r] = *reinterpret_cast<const f32x4*>(eemask + (m*256+n)*4);
      const float* dr = dmat + n*256 + kc*64;
      #pragma unroll
      for (int kt = 0; kt < 4; ++kt) dv[r][kt] = dr[kt*16 + l15];
    }
    bf16x8 Af[8];
    #pragma unroll
    for (int kk = 0; kk < 8; ++kk)
      Af[kk] = *reinterpret_cast<const bf16x8*>(elS + (((arow << 9) | (kk*64 + lg*16)) ^ ((arow & 7) << 4)));

    f32x4 acc0 = {0,0,0,0}, acc1 = {0,0,0,0}, acc2 = {0,0,0,0}, acc3 = {0,0,0,0};
    #pragma unroll
    for (int kk = 0; kk < 8; ++kk){
      int cc = kk*64 + lg*16;
      bf16x8 B0 = *reinterpret_cast<const bf16x8*>(weS + ((rowb[0] + cc) ^ rowx[0]));
      bf16x8 B1 = *reinterpret_cast<const bf16x8*>(weS + ((rowb[1] + cc) ^ rowx[1]));
      bf16x8 B2 = *reinterpret_cast<const bf16x8*>(weS + ((rowb[2] + cc) ^ rowx[2]));
      bf16x8 B3 = *reinterpret_cast<const bf16x8*>(weS + ((rowb[3] + cc) ^ rowx[3]));
      acc0 = __builtin_amdgcn_mfma_f32_16x16x32_bf16(Af[kk], B0, acc0, 0, 0, 0);
      acc1 = __builtin_amdgcn_mfma_f32_16x16x32_bf16(Af[kk], B1, acc1, 0, 0, 0);
      acc2 = __builtin_amdgcn_mfma_f32_16x16x32_bf16(Af[kk], B2, acc2, 0, 0, 0);
      acc3 = __builtin_amdgcn_mfma_f32_16x16x32_bf16(Af[kk], B3, acc3, 0, 0, 0);
    }
    #pragma unroll
    for (int r = 0; r < 4; ++r){
      float Ed0 = acc0[r] + dv[r][0] + spv[0];
      float Ed1 = acc1[r] + dv[r][1] + spv[1];
      float Ed2 = acc2[r] + dv[r][2] + spv[2];
      float Ed3 = acc3[r] + dv[r][3] + spv[3];
      #pragma unroll
      for (int t = 0; t < 4; ++t){
        if (me[r][t] > -1e29f){
          runmax[0] = fmaxf(runmax[0], fmaf(me[r][t], wtv[t][0], Ed0));
          runmax[1] = fmaxf(runmax[1], fmaf(me[r][t], wtv[t][1], Ed1));
          runmax[2] = fmaxf(runmax[2], fmaf(me[r][t], wtv[t][2], Ed2));
          runmax[3] = fmaxf(runmax[3], fmaf(me[r][t], wtv[t][3], Ed3));
        }
      }
    }
    __syncthreads();   // elS consumed; safe to overwrite next chunk
  }
  #pragma unroll
  for (int kt = 0; kt < 4; ++kt){
    float v = runmax[kt];
    v = fmaxf(v, __shfl_xor(v, 16));
    v = fmaxf(v, __shfl_xor(v, 32));
    if (l < 16) red[w][kt*16 + l] = v;
  }
  __syncthreads();
  if (tid < 64){
    float v = fmaxf(fmaxf(red[0][tid], red[1][tid]), fmaxf(red[2][tid], red[3][tid]));
    float nv = fmaxf(v, 0.f);
    int kcol = kc*64 + tid;
    float outv = (*flag) ? nv : cf[m*256+kcol];
    cf[m*256+kcol] = outv;
    cfcb[m*768 + 256*(it+1) + kcol] = __float2bfloat16(outv);
  }
}

// ---------------- final MFMA: ch = relu(cfc@Wch+b); feats = relu(ch@Wc2+b); sem = ch@Wsem+b
__global__ __launch_bounds__(256) void k_final_mfma(
  const __hip_bfloat16* __restrict__ cfcb, const __hip_bfloat16* __restrict__ WchT,
  const float* __restrict__ bch, const __hip_bfloat16* __restrict__ Wc2T,
  const float* __restrict__ bc2, const __hip_bfloat16* __restrict__ WsemT,
  const float* __restrict__ bsem, float* __restrict__ feats_out,
  float* __restrict__ sem_out)
{
  __shared__ char chs[8192];
  int tid = threadIdx.x; int w = tid>>6, l = tid&63, l15 = l&15, lg = l>>4;
  int m0 = blockIdx.x*16;

  f32x4 acc[4] = {{0,0,0,0},{0,0,0,0},{0,0,0,0},{0,0,0,0}};
  const __hip_bfloat16* Aptr = cfcb + (m0 + l15)*768;
  #pragma unroll 2
  for (int ks = 0; ks < 24; ++ks){
    int k0 = ks*32 + lg*8;
    bf16x8 Af = *reinterpret_cast<const bf16x8*>(Aptr + k0);
    #pragma unroll
    for (int nt = 0; nt < 4; ++nt){
      int col = w*64 + nt*16 + l15;
      bf16x8 Bf = *reinterpret_cast<const bf16x8*>(WchT + col*768 + k0);
      acc[nt] = __builtin_amdgcn_mfma_f32_16x16x32_bf16(Af, Bf, acc[nt], 0, 0, 0);
    }
  }
  #pragma unroll
  for (int nt = 0; nt < 4; ++nt){
    int col = w*64 + nt*16 + l15;
    float bias = bch[col];
    #pragma unroll
    for (int r = 0; r < 4; ++r){
      int row = lg*4 + r;
      float v = fmaxf(acc[nt][r] + bias, 0.f);
      int byte = ((row*256 + col)*2) ^ ((row&7)<<4);
      *reinterpret_cast<__hip_bfloat16*>(chs + byte) = __float2bfloat16(v);
    }
  }
  __syncthreads();

  f32x4 accf[4] = {{0,0,0,0},{0,0,0,0},{0,0,0,0},{0,0,0,0}};
  f32x4 accs = {0,0,0,0};
  int cols_sem = w*16 + l15;
  #pragma unroll 2
  for (int ks = 0; ks < 8; ++ks){
    int k0 = ks*32 + lg*8;
    int byteA = (l15*512 + k0*2) ^ ((l15&7)<<4);
    bf16x8 Af = *reinterpret_cast<const bf16x8*>(chs + byteA);
    #pragma unroll
    for (int nt = 0; nt < 4; ++nt){
      int col = w*64 + nt*16 + l15;
      bf16x8 Bf = *reinterpret_cast<const bf16x8*>(Wc2T + col*256 + k0);
      accf[nt] = __builtin_amdgcn_mfma_f32_16x16x32_bf16(Af, Bf, accf[nt], 0, 0, 0);
    }
    bf16x8 Bs = *reinterpret_cast<const bf16x8*>(WsemT + cols_sem*256 + k0);
    accs = __builtin_amdgcn_mfma_f32_16x16x32_bf16(Af, Bs, accs, 0, 0, 0);
  }
  #pragma unroll
  for (int nt = 0; nt < 4; ++nt){
    int col = w*64 + nt*16 + l15;
    float bias = bc2[col];
    #pragma unroll
    for (int r = 0; r < 4; ++r){
      int row = m0 + lg*4 + r;
      feats_out[row*256 + col] = fmaxf(accf[nt][r] + bias, 0.f);
    }
  }
  if (cols_sem < 50){
    float bias = bsem[cols_sem];
    #pragma unroll
    for (int r = 0; r < 4; ++r){
      int row = m0 + lg*4 + r;
      sem_out[row*50 + cols_sem] = accs[r] + bias;
    }
  }
}

extern "C" void kernel_launch(void* const* d_in, const int* in_sizes, int n_in,
                              void* d_out, int out_size, void* d_ws, size_t ws_size,
                              hipStream_t stream)
{
  const float* pf  = (const float*)d_in[0];
  const float* gc  = (const float*)d_in[1];
  const float* gn  = (const float*)d_in[2];
  const float* Wp  = (const float*)d_in[3];
  const float* bp  = (const float*)d_in[4];
  const float* Wex = (const float*)d_in[5];
  const float* bex = (const float*)d_in[6];
  const float* Wsem= (const float*)d_in[7];
  const float* bsem= (const float*)d_in[8];
  const float* Wel = (const float*)d_in[9];
  const float* bel = (const float*)d_in[10];
  const float* Wee = (const float*)d_in[11];
  const float* bee = (const float*)d_in[12];
  const float* Wne = (const float*)d_in[13];
  const float* bne = (const float*)d_in[14];
  const float* Wch = (const float*)d_in[15];
  const float* bch = (const float*)d_in[16];
  const float* Wc2 = (const float*)d_in[17];
  const float* bc2 = (const float*)d_in[18];

  float* out = (float*)d_out;
  float* feats_out = out;             // 65536
  float* sem_out   = out + 65536;     // 12800
  float* ex_out    = out + 78336;     // 256
  float* ee_out    = out + 78592;     // 262144

  char* ws = (char*)d_ws;
  float* cf    = (float*)(ws);                       // 256 KB
  float* a_    = (float*)(ws + ( 256u<<10));         // 256 KB
  float* b2_   = (float*)(ws + ( 512u<<10));         // 256 KB
  float* b2T   = (float*)(ws + ( 768u<<10));         // 256 KB
  float* sp_   = (float*)(ws + (1024u<<10));         // 256 KB
  float* dmat  = (float*)(ws + (1280u<<10));         // 256 KB
  float* eem   = (float*)(ws + (1536u<<10));         // 1 MB
  __hip_bfloat16* WeT   = (__hip_bfloat16*)(ws + (2560u<<10)); // 256 KB
  __hip_bfloat16* cfcb  = (__hip_bfloat16*)(ws + (2816u<<10)); // 384 KB
  __hip_bfloat16* WchT  = (__hip_bfloat16*)(ws + (3200u<<10)); // 384 KB
  __hip_bfloat16* Wc2T  = (__hip_bfloat16*)(ws + (3584u<<10)); // 128 KB
  __hip_bfloat16* WsemT = (__hip_bfloat16*)(ws + (3712u<<10)); //  32 KB
  int* ok   = (int*)(ws + (3744u<<10));
  int* flag = ok + 256;
  float* pchild = (float*)(ws + (3776u<<10));        // 2 MB (time-shared with pee)
  float* pee    = pchild;

  k_front<<<672,256,0,stream>>>(pf,gc,gn,Wp,Wne,Wch,Wc2,Wsem,
                                pchild,WeT,WchT,Wc2T,WsemT);
  k_reduce_ab<<<512,256,0,stream>>>(pchild,bp,Wex,bex,Wel,cf,cfcb,ex_out,ok,flag,a_,b2_,b2T);
  k_ee_part<<<512,256,0,stream>>>(a_,b2T,bel,Wee,pee);
  k_eecomb_sd0<<<512,256,0,stream>>>(pee,bee,ok,eem,ee_out,flag,cf,Wne,bne,sp_,dmat);
  k_fused_v4<<<1024,256,0,stream>>>(a_,bel,b2_,WeT,sp_,dmat,eem,Wne,cf,cfcb,flag,0);
  k_sd<<<256,256,0,stream>>>(cf,Wne,bne,sp_,dmat,1);
  k_fused_v4<<<1024,256,0,stream>>>(a_,bel,b2_,WeT + 65536,sp_,dmat,eem,
                                    Wne + 197632,cf,cfcb,flag,1);
  k_final_mfma<<<16,256,0,stream>>>(cfcb,WchT,bch,Wc2T,bc2,WsemT,bsem,feats_out,sem_out);
}